// Round 6
// baseline (1992.981 us; speedup 1.0000x reference)
//
#include <hip/hip_runtime.h>
#include <cstdint>
#include <cstddef>

#define NB 128
#define NC 16
#define NT 2048
#define NH 256
#define NG 1024
#define NO 10

typedef _Float16 f16;
typedef _Float16 h2 __attribute__((ext_vector_type(2)));
typedef _Float16 h8 __attribute__((ext_vector_type(8)));
typedef int i32x4 __attribute__((ext_vector_type(4)));
typedef long long2_ __attribute__((ext_vector_type(2)));

static __device__ __forceinline__ float fdot2(h2 a, h2 b, float c) {
#if __has_builtin(__builtin_amdgcn_fdot2)
  return __builtin_amdgcn_fdot2(a, b, c, false);
#else
  return c + (float)a[0] * (float)b[0] + (float)a[1] * (float)b[1];
#endif
}

static __device__ __forceinline__ int sdot4(int a, int b, int c) {
#if __has_builtin(__builtin_amdgcn_sdot4)
  return __builtin_amdgcn_sdot4(a, b, c, false);
#else
  int r = c;
#pragma unroll
  for (int i = 0; i < 4; ++i)
    r += (int)(int8_t)(a >> (8 * i)) * (int)(int8_t)(b >> (8 * i));
  return r;
#endif
}

// K=64 i8 MFMA (gfx950). Fallback: two chained K=32 on the lo/hi halves.
static __device__ __forceinline__ i32x4 mfma_i8_k64(i32x4 a, i32x4 b, i32x4 c) {
#if __has_builtin(__builtin_amdgcn_mfma_i32_16x16x64_i8)
  return __builtin_amdgcn_mfma_i32_16x16x64_i8(a, b, c, 0, 0, 0);
#else
  long2_ al = __builtin_bit_cast(long2_, a);
  long2_ bl = __builtin_bit_cast(long2_, b);
  c = __builtin_amdgcn_mfma_i32_16x16x32_i8(al[0], bl[0], c, 0, 0, 0);
  c = __builtin_amdgcn_mfma_i32_16x16x32_i8(al[1], bl[1], c, 0, 0, 0);
  return c;
#endif
}

// VALU lane swap 2k<->2k+1 via DPP quad_perm [1,0,3,2].
static __device__ __forceinline__ float pairswap(float v) {
  int r = __builtin_amdgcn_update_dpp(0, __builtin_bit_cast(int, v),
                                      0xB1, 0xF, 0xF, true);
  return __builtin_bit_cast(float, r);
}

static __device__ __forceinline__ float sigm(float x) {
  return __builtin_amdgcn_rcpf(1.f + __expf(-x));
}
static __device__ __forceinline__ float tanh_(float x) {
  return 1.f - 2.f * __builtin_amdgcn_rcpf(1.f + __expf(2.f * x));
}

// Quantize w_hh (1024x256 f32 row-major) to i8 with per-row scale.
__global__ void prepack_whh_i8(const float* __restrict__ whh,
                               int8_t* __restrict__ wq,
                               float* __restrict__ scale) {
  int row = blockIdx.x;   // 0..1023
  int k   = threadIdx.x;  // 0..255
  float v = whh[row * NH + k];
  float m = fabsf(v);
  for (int off = 32; off; off >>= 1) m = fmaxf(m, __shfl_xor(m, off, 64));
  __shared__ float smax[4];
  if ((k & 63) == 0) smax[k >> 6] = m;
  __syncthreads();
  float mm = fmaxf(fmaxf(smax[0], smax[1]), fmaxf(smax[2], smax[3]));
  float s = fmaxf(mm, 1e-20f) / 127.f;
  int qv = (int)rintf(v / s);
  qv = min(127, max(-127, qv));
  wq[row * NH + k] = (int8_t)qv;
  if (k == 0) scale[row] = s;
}

// HYBRID PIPE-SPLIT. One WG per batch, 512 threads = 8 waves, 2/SIMD.
// Waves are placed round-robin on SIMDs (wave i -> SIMD i%4), so each SIMD
// hosts one wave of EACH role; MFMA (matrix pipe) and sdot4 (VALU pipe)
// run concurrently (m114: separate pipes overlap across waves).
//
// Role M (waves 0-3): units [32w, 32w+32) via broadcast-A i8 MFMA
//   (v_mfma_i32_16x16x64_i8, 8 tiles x 4 k-chained = 32 MFMA/step).
//   Lane l = 16*grp+r, sel=grp&1 finalizes unit 32w+16*sel+r fully
//   in-register (round-5 verified path, absmax 0.015625).
// Role V (waves 4-7): units [128+32v, 128+32v+32) via the round-0
//   baseline sdot4 path: thread pair (2 lanes/unit, k-halves), per-half
//   dequant + DPP pairswap (round-0 verified path, absmax 0.015625).
//
// The two roles' loops are textually DISJOINT so the allocator overlays
// bw[128] (M) with wi_/wf_/wg_/wo_[128] (V). Barrier counts per
// iteration are identical in both branches (s_barrier counts waves).
__global__ __launch_bounds__(512, 2)
void lstm_main(const float* __restrict__ x,
               const float* __restrict__ w_ih,
               const float* __restrict__ b_ih,
               const float* __restrict__ b_hh,
               const float* __restrict__ w_out,
               const float* __restrict__ b_out,
               const int8_t* __restrict__ wq,
               const float* __restrict__ scales,
               float* __restrict__ out) {
  const int t = threadIdx.x;   // 0..511
  const int l = t & 63;        // lane in wave
  const int w = t >> 6;        // wave 0..7
  const int b = blockIdx.x;

  __shared__ __align__(16) int8_t hq[2][NH];  // h state, 2 phases, linear
  __shared__ __align__(16) f16 xs[64][NC];    // 2 KB staged x
  __shared__ float hT[NH];
  __shared__ float lg[NO];

  // ---------------- common init ----------------
  ((int8_t*)hq)[t] = 0;
#pragma unroll
  for (int r = 0; r < 2; ++r) {
    int e = t + 512 * r;  // 0..1023 over (c, tt)
    int cc = e >> 6, tt = e & 63;
    xs[tt][cc] = (f16)x[(size_t)(b * NC + cc) * NT + tt];
  }
  __syncthreads();

  const float K = 1.f / 127.f;

  if (w < 4) {
    // ================= ROLE M: MFMA waves, units [0,128) =================
    const int row16 = l & 15;
    const int grp = l >> 4;
    const int sel = grp & 1;
    const int uu = 32 * w + 16 * sel + row16;  // unit this lane finalizes

    // B fragments: tile (gt,hf) rows = 256*gt + 32*w + 16*hf + row16,
    // lane k-segment = kt*64 + grp*16. Same k formula as A -> consistent
    // HW k-permutations cancel in the dot.
    i32x4 bw[4][2][4];  // 128 regs (AGPR-eligible)
#pragma unroll
    for (int gt = 0; gt < 4; ++gt)
#pragma unroll
      for (int hf = 0; hf < 2; ++hf) {
        const int8_t* rp =
            wq + (size_t)(256 * gt + 32 * w + 16 * hf + row16) * NH + grp * 16;
#pragma unroll
        for (int kt = 0; kt < 4; ++kt)
          bw[gt][hf][kt] = *(const i32x4*)(rp + kt * 64);
      }

    h2 wih[4][8];  // full 16-channel w_ih rows for this lane's unit
#pragma unroll
    for (int gt = 0; gt < 4; ++gt) {
      const float* rp = w_ih + (size_t)(256 * gt + uu) * NC;
#pragma unroll
      for (int q = 0; q < 8; ++q) {
        h2 t2 = {(f16)rp[2 * q], (f16)rp[2 * q + 1]};
        wih[gt][q] = t2;
      }
    }
    float sc[4], bb[4];
#pragma unroll
    for (int gt = 0; gt < 4; ++gt) {
      sc[gt] = scales[256 * gt + uu] * K;
      bb[gt] = b_ih[256 * gt + uu] + b_hh[256 * gt + uu];
    }

    float c_ = 0.f, h_last = 0.f;
#pragma unroll 1
    for (int s = 0; s < NT; ++s) {
      const int p = s & 1;
      // A fragments (broadcast within 16-lane groups, bank-disjoint)
      const int8_t* hp = hq[p] + grp * 16;
      i32x4 a_[4];
#pragma unroll
      for (int kt = 0; kt < 4; ++kt) a_[kt] = *(const i32x4*)(hp + kt * 64);

      // x-projection (VALU; independent of MFMAs)
      h8 xlo = *(const h8*)&xs[s & 63][0];
      h8 xhi = *(const h8*)&xs[s & 63][8];
      float xp[4];
#pragma unroll
      for (int gt = 0; gt < 4; ++gt) {
        float acc = bb[gt];
#pragma unroll
        for (int q = 0; q < 4; ++q) {
          h2 xa = {xlo[2 * q], xlo[2 * q + 1]};
          acc = fdot2(xa, wih[gt][q], acc);
        }
#pragma unroll
        for (int q = 0; q < 4; ++q) {
          h2 xa = {xhi[2 * q], xhi[2 * q + 1]};
          acc = fdot2(xa, wih[gt][q + 4], acc);
        }
        xp[gt] = acc;
      }

      // 8 tiles x 4 chained k-steps; extract acc[0] per tile, keep sel's
      float gv[4];
#pragma unroll
      for (int gt = 0; gt < 4; ++gt) {
        i32x4 a0 = {0, 0, 0, 0}, a1 = {0, 0, 0, 0};
#pragma unroll
        for (int kt = 0; kt < 4; ++kt) a0 = mfma_i8_k64(a_[kt], bw[gt][0][kt], a0);
#pragma unroll
        for (int kt = 0; kt < 4; ++kt) a1 = mfma_i8_k64(a_[kt], bw[gt][1][kt], a1);
        int d = sel ? a1[0] : a0[0];
        gv[gt] = xp[gt] + (float)d * sc[gt];
      }

      float ig = sigm(gv[0]);
      float fg = sigm(gv[1]);
      float gg = tanh_(gv[2]);
      float og = sigm(gv[3]);
      c_ = fg * c_ + ig * gg;
      float hh = og * tanh_(c_);
      h_last = hh;
      if (l < 32) hq[1 - p][uu] = (int8_t)(int)rintf(hh * 127.f);

      if ((s & 63) == 63 && s != NT - 1) {
        __syncthreads();
#pragma unroll
        for (int r = 0; r < 2; ++r) {
          int e = t + 512 * r;
          int cc = e >> 6, tt = e & 63;
          xs[tt][cc] = (f16)x[(size_t)(b * NC + cc) * NT + (s + 1) + tt];
        }
      }
      __syncthreads();
    }
    if (l < 32) hT[uu] = h_last;
  } else {
    // ================= ROLE V: sdot4 waves, units [128,256) ==============
    const int q = l >> 1;        // unit-within-wave 0..31
    const int half = l & 1;      // k-half
    const int uv = 128 + 32 * (w - 4) + q;

    int wi_[32], wf_[32], wg_[32], wo_[32];  // 4 gate half-rows, i8x4
    {
      const int4* pi = (const int4*)(wq + (size_t)uv * NH + 128 * half);
      const int4* pf = (const int4*)(wq + (size_t)(256 + uv) * NH + 128 * half);
      const int4* pg = (const int4*)(wq + (size_t)(512 + uv) * NH + 128 * half);
      const int4* po = (const int4*)(wq + (size_t)(768 + uv) * NH + 128 * half);
#pragma unroll
      for (int c = 0; c < 8; ++c) {
        int4 vi = pi[c], vf = pf[c], vg = pg[c], vo = po[c];
        wi_[4 * c + 0] = vi.x; wi_[4 * c + 1] = vi.y; wi_[4 * c + 2] = vi.z; wi_[4 * c + 3] = vi.w;
        wf_[4 * c + 0] = vf.x; wf_[4 * c + 1] = vf.y; wf_[4 * c + 2] = vf.z; wf_[4 * c + 3] = vf.w;
        wg_[4 * c + 0] = vg.x; wg_[4 * c + 1] = vg.y; wg_[4 * c + 2] = vg.z; wg_[4 * c + 3] = vg.w;
        wo_[4 * c + 0] = vo.x; wo_[4 * c + 1] = vo.y; wo_[4 * c + 2] = vo.z; wo_[4 * c + 3] = vo.w;
      }
    }
    h2 wihv[4][4];  // w_ih half-rows (8 ch) x 4 gates
#pragma unroll
    for (int g4 = 0; g4 < 4; ++g4) {
      int row = uv + 256 * g4;
#pragma unroll
      for (int uu2 = 0; uu2 < 4; ++uu2) {
        h2 t2 = {(f16)w_ih[row * NC + 8 * half + 2 * uu2],
                 (f16)w_ih[row * NC + 8 * half + 2 * uu2 + 1]};
        wihv[g4][uu2] = t2;
      }
    }
    float sci = scales[uv] * K;
    float scf = scales[256 + uv] * K;
    float scg = scales[512 + uv] * K;
    float sco = scales[768 + uv] * K;
    // biases only in half 0 (added exactly once per gate sum)
    float bi_ = half ? 0.f : b_ih[uv] + b_hh[uv];
    float bf_ = half ? 0.f : b_ih[256 + uv] + b_hh[256 + uv];
    float bg_ = half ? 0.f : b_ih[512 + uv] + b_hh[512 + uv];
    float bo_ = half ? 0.f : b_ih[768 + uv] + b_hh[768 + uv];

    float c_ = 0.f, h_last = 0.f;
#pragma unroll 1
    for (int s = 0; s < NT; ++s) {
      const int p = s & 1;
      const int4* hrd = (const int4*)(hq[p] + 128 * half);  // 2-addr bcast

      float fi = bi_, ff = bf_, fg_ = bg_, fo = bo_;
      {
        h8 xv = *(const h8*)&xs[s & 63][8 * half];
#pragma unroll
        for (int uu2 = 0; uu2 < 4; ++uu2) {
          h2 xp = {xv[2 * uu2], xv[2 * uu2 + 1]};
          fi = fdot2(xp, wihv[0][uu2], fi);
          ff = fdot2(xp, wihv[1][uu2], ff);
          fg_ = fdot2(xp, wihv[2][uu2], fg_);
          fo = fdot2(xp, wihv[3][uu2], fo);
        }
      }

      int ai = 0, af = 0, ag = 0, ao = 0;
#pragma unroll
      for (int c = 0; c < 8; ++c) {
        int4 hv = hrd[c];
        ai = sdot4(hv.x, wi_[4 * c + 0], ai); ai = sdot4(hv.y, wi_[4 * c + 1], ai);
        ai = sdot4(hv.z, wi_[4 * c + 2], ai); ai = sdot4(hv.w, wi_[4 * c + 3], ai);
        af = sdot4(hv.x, wf_[4 * c + 0], af); af = sdot4(hv.y, wf_[4 * c + 1], af);
        af = sdot4(hv.z, wf_[4 * c + 2], af); af = sdot4(hv.w, wf_[4 * c + 3], af);
        ag = sdot4(hv.x, wg_[4 * c + 0], ag); ag = sdot4(hv.y, wg_[4 * c + 1], ag);
        ag = sdot4(hv.z, wg_[4 * c + 2], ag); ag = sdot4(hv.w, wg_[4 * c + 3], ag);
        ao = sdot4(hv.x, wo_[4 * c + 0], ao); ao = sdot4(hv.y, wo_[4 * c + 1], ao);
        ao = sdot4(hv.z, wo_[4 * c + 2], ao); ao = sdot4(hv.w, wo_[4 * c + 3], ao);
      }

      float vi = fi + (float)ai * sci;
      float vf = ff + (float)af * scf;
      float vg = fg_ + (float)ag * scg;
      float vo = fo + (float)ao * sco;
      vi += pairswap(vi); vf += pairswap(vf); vg += pairswap(vg); vo += pairswap(vo);

      float ig = sigm(vi);
      float fgate = sigm(vf);
      float gv = tanh_(vg);
      float og = sigm(vo);
      c_ = fgate * c_ + ig * gv;
      float hh = og * tanh_(c_);
      h_last = hh;
      if (!half) hq[1 - p][uv] = (int8_t)(int)rintf(hh * 127.f);

      if ((s & 63) == 63 && s != NT - 1) {
        __syncthreads();
#pragma unroll
        for (int r = 0; r < 2; ++r) {
          int e = t + 512 * r;
          int cc = e >> 6, tt = e & 63;
          xs[tt][cc] = (f16)x[(size_t)(b * NC + cc) * NT + (s + 1) + tt];
        }
      }
      __syncthreads();
    }
    if (!half) hT[uv] = h_last;
  }

  // ---------------- head: logits + log_softmax ----------------
  __syncthreads();
  if (t < NO) {
    float acc = b_out[t];
    for (int k = 0; k < NH; ++k) acc += hT[k] * w_out[t * NH + k];
    lg[t] = acc;
  }
  __syncthreads();
  if (t == 0) {
    float m = lg[0];
    for (int o = 1; o < NO; ++o) m = fmaxf(m, lg[o]);
    float ssum = 0.f;
    for (int o = 0; o < NO; ++o) ssum += __expf(lg[o] - m);
    float lse = m + __logf(ssum);
    for (int o = 0; o < NO; ++o) out[b * NO + o] = lg[o] - lse;
  }
}

extern "C" void kernel_launch(void* const* d_in, const int* in_sizes, int n_in,
                              void* d_out, int out_size, void* d_ws, size_t ws_size,
                              hipStream_t stream) {
  const float* x    = (const float*)d_in[0];
  const float* wih  = (const float*)d_in[1];
  const float* whh  = (const float*)d_in[2];
  const float* bih  = (const float*)d_in[3];
  const float* bhh  = (const float*)d_in[4];
  const float* wout = (const float*)d_in[5];
  const float* bout = (const float*)d_in[6];
  float* out = (float*)d_out;
  int8_t* wq = (int8_t*)d_ws;                       // 256 KB i8 w_hh
  float* scales = (float*)((char*)d_ws + NG * NH);  // 4 KB row scales

  hipLaunchKernelGGL(prepack_whh_i8, dim3(NG), dim3(NH), 0, stream, whh, wq, scales);
  hipLaunchKernelGGL(lstm_main, dim3(NB), dim3(512), 0, stream,
                     x, wih, bih, bhh, wout, bout, wq, scales, out);
}

// Round 8
// 1867.670 us; speedup vs baseline: 1.0671x; 1.0671x over previous
//
#include <hip/hip_runtime.h>
#include <cstdint>
#include <cstddef>

#define NB 128
#define NC 16
#define NT 2048
#define NH 256
#define NG 1024
#define NO 10

typedef _Float16 f16;
typedef _Float16 h2 __attribute__((ext_vector_type(2)));
typedef _Float16 h8 __attribute__((ext_vector_type(8)));
typedef int i32x4 __attribute__((ext_vector_type(4)));
typedef long long2_ __attribute__((ext_vector_type(2)));

static __device__ __forceinline__ float fdot2(h2 a, h2 b, float c) {
#if __has_builtin(__builtin_amdgcn_fdot2)
  return __builtin_amdgcn_fdot2(a, b, c, false);
#else
  return c + (float)a[0] * (float)b[0] + (float)a[1] * (float)b[1];
#endif
}

static __device__ __forceinline__ int sdot4(int a, int b, int c) {
#if __has_builtin(__builtin_amdgcn_sdot4)
  return __builtin_amdgcn_sdot4(a, b, c, false);
#else
  int r = c;
#pragma unroll
  for (int i = 0; i < 4; ++i)
    r += (int)(int8_t)(a >> (8 * i)) * (int)(int8_t)(b >> (8 * i));
  return r;
#endif
}

// K=64 i8 MFMA (gfx950). Fallback: two chained K=32 on the lo/hi halves.
static __device__ __forceinline__ i32x4 mfma_i8_k64(i32x4 a, i32x4 b, i32x4 c) {
#if __has_builtin(__builtin_amdgcn_mfma_i32_16x16x64_i8)
  return __builtin_amdgcn_mfma_i32_16x16x64_i8(a, b, c, 0, 0, 0);
#else
  long2_ al = __builtin_bit_cast(long2_, a);
  long2_ bl = __builtin_bit_cast(long2_, b);
  c = __builtin_amdgcn_mfma_i32_16x16x32_i8(al[0], bl[0], c, 0, 0, 0);
  c = __builtin_amdgcn_mfma_i32_16x16x32_i8(al[1], bl[1], c, 0, 0, 0);
  return c;
#endif
}

// VALU lane swap 2k<->2k+1 via DPP quad_perm [1,0,3,2].
static __device__ __forceinline__ float pairswap(float v) {
  int r = __builtin_amdgcn_update_dpp(0, __builtin_bit_cast(int, v),
                                      0xB1, 0xF, 0xF, true);
  return __builtin_bit_cast(float, r);
}

static __device__ __forceinline__ float sigm(float x) {
  return __builtin_amdgcn_rcpf(1.f + __expf(-x));
}
static __device__ __forceinline__ float tanh_(float x) {
  return 1.f - 2.f * __builtin_amdgcn_rcpf(1.f + __expf(2.f * x));
}

// Quantize w_hh (1024x256 f32 row-major) to i8 with per-row scale.
__global__ void prepack_whh_i8(const float* __restrict__ whh,
                               int8_t* __restrict__ wq,
                               float* __restrict__ scale) {
  int row = blockIdx.x;   // 0..1023
  int k   = threadIdx.x;  // 0..255
  float v = whh[row * NH + k];
  float m = fabsf(v);
  for (int off = 32; off; off >>= 1) m = fmaxf(m, __shfl_xor(m, off, 64));
  __shared__ float smax[4];
  if ((k & 63) == 0) smax[k >> 6] = m;
  __syncthreads();
  float mm = fmaxf(fmaxf(smax[0], smax[1]), fmaxf(smax[2], smax[3]));
  float s = fmaxf(mm, 1e-20f) / 127.f;
  int qv = (int)rintf(v / s);
  qv = min(127, max(-127, qv));
  wq[row * NH + k] = (int8_t)qv;
  if (k == 0) scale[row] = s;
}

// HYBRID PIPE-SPLIT v2 — PLACEMENT-AWARE ROLES.
// Round-6 evidence: role=(w<4) left some SIMDs with two same-role waves
// (placement is NOT round-robin i%4): no cross-pipe overlap, barrier tied
// to the slow VV SIMDs -> 1993us. Fix: each wave reads its PHYSICAL SIMD
// id (HW_REG_HW_ID bits[5:4], gfx9 layout; s_getreg verified on gfx950)
// and claims a role via LDS atomics: 1st wave on a SIMD -> role M (MFMA),
// 2nd -> role V (sdot4). Clamp guarantees exactly 4 M + 4 V waves with
// valid block ids under ANY claim distribution. Result: every SIMD hosts
// one matrix-pipe wave and one VALU-pipe wave -> concurrent pipes (m114).
//
// Role M (4 waves): units [32m, 32m+32) via broadcast-A i8 MFMA
//   (v_mfma_i32_16x16x64_i8, 8 tiles x 4 k-chained = 32 MFMA/step),
//   s_setprio(1) around the MFMA cluster (T5, role-split schedule).
// Role V (4 waves): units [128+32v, ..+32) via round-0 sdot4 path
//   (2 lanes/unit, k-halves, per-half dequant + DPP pairswap).
// Both paths verified at absmax 0.015625 (rounds 0/5/6).
__global__ __launch_bounds__(512, 2)
void lstm_main(const float* __restrict__ x,
               const float* __restrict__ w_ih,
               const float* __restrict__ b_ih,
               const float* __restrict__ b_hh,
               const float* __restrict__ w_out,
               const float* __restrict__ b_out,
               const int8_t* __restrict__ wq,
               const float* __restrict__ scales,
               float* __restrict__ out) {
  const int t = threadIdx.x;   // 0..511
  const int l = t & 63;        // lane in wave
  const int w = t >> 6;        // wave 0..7
  const int b = blockIdx.x;

  __shared__ __align__(16) int8_t hq[2][NH];  // h state, 2 phases, linear
  __shared__ __align__(16) f16 xs[64][NC];    // 2 KB staged x
  __shared__ float hT[NH];
  __shared__ float lg[NO];
  __shared__ int sctr[4];            // per-SIMD claim counters
  __shared__ int rctr[2];            // per-role block counters
  __shared__ int role_of[8], blk_of[8];

  // ---------------- common init ----------------
  if (t < 4) sctr[t] = 0;
  if (t >= 4 && t < 6) rctr[t - 4] = 0;
  ((int8_t*)hq)[t] = 0;
#pragma unroll
  for (int r = 0; r < 2; ++r) {
    int e = t + 512 * r;  // 0..1023 over (c, tt)
    int cc = e >> 6, tt = e & 63;
    xs[tt][cc] = (f16)x[(size_t)(b * NC + cc) * NT + tt];
  }
  __syncthreads();

  // ---- placement-aware role claim (one-time) ----
  if (l == 0) {
    unsigned hwid;
    asm volatile("s_getreg_b32 %0, hwreg(HW_REG_HW_ID)" : "=s"(hwid));
    int sid = (hwid >> 4) & 3;             // physical SIMD within CU
    int fst = atomicAdd(&sctr[sid], 1);    // arrival order on this SIMD
    int role = fst & 1;                    // 1st->M(0), 2nd->V(1)
    int blk = atomicAdd(&rctr[role], 1);
    if (blk >= 4) {                        // degenerate-claim safety net
      role ^= 1;
      blk = atomicAdd(&rctr[role], 1);
    }
    role_of[w] = role;
    blk_of[w] = blk;
  }
  __syncthreads();
  const int role = role_of[w];  // wave-uniform
  const int blk = blk_of[w];    // 0..3 within role

  const float K = 1.f / 127.f;

  if (role == 0) {
    // ================= ROLE M: MFMA wave, units [32blk, 32blk+32) ========
    const int row16 = l & 15;
    const int grp = l >> 4;
    const int sel = grp & 1;
    const int uu = 32 * blk + 16 * sel + row16;  // unit this lane finalizes

    // B fragments: tile (gt,hf) rows = 256*gt + 32*blk + 16*hf + row16,
    // lane k-segment = kt*64 + grp*16. Same k formula as A -> consistent
    // HW k-permutations cancel in the dot.
    i32x4 bw[4][2][4];  // 128 regs (AGPR-eligible)
#pragma unroll
    for (int gt = 0; gt < 4; ++gt)
#pragma unroll
      for (int hf = 0; hf < 2; ++hf) {
        const int8_t* rp =
            wq + (size_t)(256 * gt + 32 * blk + 16 * hf + row16) * NH + grp * 16;
#pragma unroll
        for (int kt = 0; kt < 4; ++kt)
          bw[gt][hf][kt] = *(const i32x4*)(rp + kt * 64);
      }

    h2 wih[4][8];  // full 16-channel w_ih rows for this lane's unit
#pragma unroll
    for (int gt = 0; gt < 4; ++gt) {
      const float* rp = w_ih + (size_t)(256 * gt + uu) * NC;
#pragma unroll
      for (int q = 0; q < 8; ++q) {
        h2 t2 = {(f16)rp[2 * q], (f16)rp[2 * q + 1]};
        wih[gt][q] = t2;
      }
    }
    float sc[4], bb[4];
#pragma unroll
    for (int gt = 0; gt < 4; ++gt) {
      sc[gt] = scales[256 * gt + uu] * K;
      bb[gt] = b_ih[256 * gt + uu] + b_hh[256 * gt + uu];
    }

    float c_ = 0.f, h_last = 0.f;
#pragma unroll 1
    for (int s = 0; s < NT; ++s) {
      const int p = s & 1;
      // A fragments (broadcast within 16-lane groups, bank-disjoint)
      const int8_t* hp = hq[p] + grp * 16;
      i32x4 a_[4];
#pragma unroll
      for (int kt = 0; kt < 4; ++kt) a_[kt] = *(const i32x4*)(hp + kt * 64);

      // 8 tiles x 4 chained k-steps on the matrix pipe, raised priority
      __builtin_amdgcn_s_setprio(1);
      i32x4 acc[4][2];
#pragma unroll
      for (int gt = 0; gt < 4; ++gt)
#pragma unroll
        for (int hf = 0; hf < 2; ++hf) {
          i32x4 ac = {0, 0, 0, 0};
#pragma unroll
          for (int kt = 0; kt < 4; ++kt)
            ac = mfma_i8_k64(a_[kt], bw[gt][hf][kt], ac);
          acc[gt][hf] = ac;
        }
      __builtin_amdgcn_s_setprio(0);

      // x-projection (VALU; fills issue slots while MFMAs drain)
      h8 xlo = *(const h8*)&xs[s & 63][0];
      h8 xhi = *(const h8*)&xs[s & 63][8];
      float gv[4];
#pragma unroll
      for (int gt = 0; gt < 4; ++gt) {
        float acc_x = bb[gt];
#pragma unroll
        for (int q = 0; q < 4; ++q) {
          h2 xa = {xlo[2 * q], xlo[2 * q + 1]};
          acc_x = fdot2(xa, wih[gt][q], acc_x);
        }
#pragma unroll
        for (int q = 0; q < 4; ++q) {
          h2 xa = {xhi[2 * q], xhi[2 * q + 1]};
          acc_x = fdot2(xa, wih[gt][q + 4], acc_x);
        }
        int d = sel ? acc[gt][1][0] : acc[gt][0][0];
        gv[gt] = acc_x + (float)d * sc[gt];
      }

      float ig = sigm(gv[0]);
      float fg = sigm(gv[1]);
      float gg = tanh_(gv[2]);
      float og = sigm(gv[3]);
      c_ = fg * c_ + ig * gg;
      float hh = og * tanh_(c_);
      h_last = hh;
      if (l < 32) hq[1 - p][uu] = (int8_t)(int)rintf(hh * 127.f);

      if ((s & 63) == 63 && s != NT - 1) {
        __syncthreads();
#pragma unroll
        for (int r = 0; r < 2; ++r) {
          int e = t + 512 * r;
          int cc = e >> 6, tt = e & 63;
          xs[tt][cc] = (f16)x[(size_t)(b * NC + cc) * NT + (s + 1) + tt];
        }
      }
      __syncthreads();
    }
    if (l < 32) hT[uu] = h_last;
  } else {
    // ================= ROLE V: sdot4 wave, units [128+32blk, ..+32) ======
    const int q = l >> 1;        // unit-within-wave 0..31
    const int half = l & 1;      // k-half
    const int uv = 128 + 32 * blk + q;

    int wi_[32], wf_[32], wg_[32], wo_[32];  // 4 gate half-rows, i8x4
    {
      const int4* pi = (const int4*)(wq + (size_t)uv * NH + 128 * half);
      const int4* pf = (const int4*)(wq + (size_t)(256 + uv) * NH + 128 * half);
      const int4* pg = (const int4*)(wq + (size_t)(512 + uv) * NH + 128 * half);
      const int4* po = (const int4*)(wq + (size_t)(768 + uv) * NH + 128 * half);
#pragma unroll
      for (int c = 0; c < 8; ++c) {
        int4 vi = pi[c], vf = pf[c], vg = pg[c], vo = po[c];
        wi_[4 * c + 0] = vi.x; wi_[4 * c + 1] = vi.y; wi_[4 * c + 2] = vi.z; wi_[4 * c + 3] = vi.w;
        wf_[4 * c + 0] = vf.x; wf_[4 * c + 1] = vf.y; wf_[4 * c + 2] = vf.z; wf_[4 * c + 3] = vf.w;
        wg_[4 * c + 0] = vg.x; wg_[4 * c + 1] = vg.y; wg_[4 * c + 2] = vg.z; wg_[4 * c + 3] = vg.w;
        wo_[4 * c + 0] = vo.x; wo_[4 * c + 1] = vo.y; wo_[4 * c + 2] = vo.z; wo_[4 * c + 3] = vo.w;
      }
    }
    h2 wihv[4][4];  // w_ih half-rows (8 ch) x 4 gates
#pragma unroll
    for (int g4 = 0; g4 < 4; ++g4) {
      int row = uv + 256 * g4;
#pragma unroll
      for (int uu2 = 0; uu2 < 4; ++uu2) {
        h2 t2 = {(f16)w_ih[row * NC + 8 * half + 2 * uu2],
                 (f16)w_ih[row * NC + 8 * half + 2 * uu2 + 1]};
        wihv[g4][uu2] = t2;
      }
    }
    float sci = scales[uv] * K;
    float scf = scales[256 + uv] * K;
    float scg = scales[512 + uv] * K;
    float sco = scales[768 + uv] * K;
    // biases only in half 0 (added exactly once per gate sum)
    float bi_ = half ? 0.f : b_ih[uv] + b_hh[uv];
    float bf_ = half ? 0.f : b_ih[256 + uv] + b_hh[256 + uv];
    float bg_ = half ? 0.f : b_ih[512 + uv] + b_hh[512 + uv];
    float bo_ = half ? 0.f : b_ih[768 + uv] + b_hh[768 + uv];

    float c_ = 0.f, h_last = 0.f;
#pragma unroll 1
    for (int s = 0; s < NT; ++s) {
      const int p = s & 1;
      const int4* hrd = (const int4*)(hq[p] + 128 * half);  // 2-addr bcast

      float fi = bi_, ff = bf_, fg_ = bg_, fo = bo_;
      {
        h8 xv = *(const h8*)&xs[s & 63][8 * half];
#pragma unroll
        for (int uu2 = 0; uu2 < 4; ++uu2) {
          h2 xp = {xv[2 * uu2], xv[2 * uu2 + 1]};
          fi = fdot2(xp, wihv[0][uu2], fi);
          ff = fdot2(xp, wihv[1][uu2], ff);
          fg_ = fdot2(xp, wihv[2][uu2], fg_);
          fo = fdot2(xp, wihv[3][uu2], fo);
        }
      }

      int ai = 0, af = 0, ag = 0, ao = 0;
#pragma unroll
      for (int c = 0; c < 8; ++c) {
        int4 hv = hrd[c];
        ai = sdot4(hv.x, wi_[4 * c + 0], ai); ai = sdot4(hv.y, wi_[4 * c + 1], ai);
        ai = sdot4(hv.z, wi_[4 * c + 2], ai); ai = sdot4(hv.w, wi_[4 * c + 3], ai);
        af = sdot4(hv.x, wf_[4 * c + 0], af); af = sdot4(hv.y, wf_[4 * c + 1], af);
        af = sdot4(hv.z, wf_[4 * c + 2], af); af = sdot4(hv.w, wf_[4 * c + 3], af);
        ag = sdot4(hv.x, wg_[4 * c + 0], ag); ag = sdot4(hv.y, wg_[4 * c + 1], ag);
        ag = sdot4(hv.z, wg_[4 * c + 2], ag); ag = sdot4(hv.w, wg_[4 * c + 3], ag);
        ao = sdot4(hv.x, wo_[4 * c + 0], ao); ao = sdot4(hv.y, wo_[4 * c + 1], ao);
        ao = sdot4(hv.z, wo_[4 * c + 2], ao); ao = sdot4(hv.w, wo_[4 * c + 3], ao);
      }

      float vi = fi + (float)ai * sci;
      float vf = ff + (float)af * scf;
      float vg = fg_ + (float)ag * scg;
      float vo = fo + (float)ao * sco;
      vi += pairswap(vi); vf += pairswap(vf); vg += pairswap(vg); vo += pairswap(vo);

      float ig = sigm(vi);
      float fgate = sigm(vf);
      float gv = tanh_(vg);
      float og = sigm(vo);
      c_ = fgate * c_ + ig * gv;
      float hh = og * tanh_(c_);
      h_last = hh;
      if (!half) hq[1 - p][uv] = (int8_t)(int)rintf(hh * 127.f);

      if ((s & 63) == 63 && s != NT - 1) {
        __syncthreads();
#pragma unroll
        for (int r = 0; r < 2; ++r) {
          int e = t + 512 * r;
          int cc = e >> 6, tt = e & 63;
          xs[tt][cc] = (f16)x[(size_t)(b * NC + cc) * NT + (s + 1) + tt];
        }
      }
      __syncthreads();
    }
    if (!half) hT[uv] = h_last;
  }

  // ---------------- head: logits + log_softmax ----------------
  __syncthreads();
  if (t < NO) {
    float acc = b_out[t];
    for (int k = 0; k < NH; ++k) acc += hT[k] * w_out[t * NH + k];
    lg[t] = acc;
  }
  __syncthreads();
  if (t == 0) {
    float m = lg[0];
    for (int o = 1; o < NO; ++o) m = fmaxf(m, lg[o]);
    float ssum = 0.f;
    for (int o = 0; o < NO; ++o) ssum += __expf(lg[o] - m);
    float lse = m + __logf(ssum);
    for (int o = 0; o < NO; ++o) out[b * NO + o] = lg[o] - lse;
  }
}

extern "C" void kernel_launch(void* const* d_in, const int* in_sizes, int n_in,
                              void* d_out, int out_size, void* d_ws, size_t ws_size,
                              hipStream_t stream) {
  const float* x    = (const float*)d_in[0];
  const float* wih  = (const float*)d_in[1];
  const float* whh  = (const float*)d_in[2];
  const float* bih  = (const float*)d_in[3];
  const float* bhh  = (const float*)d_in[4];
  const float* wout = (const float*)d_in[5];
  const float* bout = (const float*)d_in[6];
  float* out = (float*)d_out;
  int8_t* wq = (int8_t*)d_ws;                       // 256 KB i8 w_hh
  float* scales = (float*)((char*)d_ws + NG * NH);  // 4 KB row scales

  hipLaunchKernelGGL(prepack_whh_i8, dim3(NG), dim3(NH), 0, stream, whh, wq, scales);
  hipLaunchKernelGGL(lstm_main, dim3(NB), dim3(512), 0, stream,
                     x, wih, bih, bhh, wout, bout, wq, scales, out);
}

// Round 9
// 1822.775 us; speedup vs baseline: 1.0934x; 1.0246x over previous
//
#include <hip/hip_runtime.h>
#include <cstdint>
#include <cstddef>

#define NB 128
#define NC 16
#define NT 2048
#define NH 256
#define NG 1024
#define NO 10

typedef _Float16 f16;
typedef _Float16 h2 __attribute__((ext_vector_type(2)));
typedef _Float16 h8 __attribute__((ext_vector_type(8)));

static __device__ __forceinline__ float fdot2(h2 a, h2 b, float c) {
#if __has_builtin(__builtin_amdgcn_fdot2)
  return __builtin_amdgcn_fdot2(a, b, c, false);
#else
  return c + (float)a[0] * (float)b[0] + (float)a[1] * (float)b[1];
#endif
}

static __device__ __forceinline__ int sdot4(int a, int b, int c) {
#if __has_builtin(__builtin_amdgcn_sdot4)
  return __builtin_amdgcn_sdot4(a, b, c, false);
#else
  int r = c;
#pragma unroll
  for (int i = 0; i < 4; ++i)
    r += (int)(int8_t)(a >> (8 * i)) * (int)(int8_t)(b >> (8 * i));
  return r;
#endif
}

// VALU lane swap 2k<->2k+1 via DPP quad_perm [1,0,3,2] (no DS traffic).
static __device__ __forceinline__ float pairswap(float v) {
  int r = __builtin_amdgcn_update_dpp(0, __builtin_bit_cast(int, v),
                                      0xB1, 0xF, 0xF, true);
  return __builtin_bit_cast(float, r);
}

static __device__ __forceinline__ float sigm(float x) {
  return __builtin_amdgcn_rcpf(1.f + __expf(-x));
}
static __device__ __forceinline__ float tanh_(float x) {
  return 1.f - 2.f * __builtin_amdgcn_rcpf(1.f + __expf(2.f * x));
}

// Quantize w_hh (1024x256 f32 row-major) to i8 with per-row scale.
__global__ void prepack_whh_i8(const float* __restrict__ whh,
                               int8_t* __restrict__ wq,
                               float* __restrict__ scale) {
  int row = blockIdx.x;   // 0..1023
  int k   = threadIdx.x;  // 0..255
  float v = whh[row * NH + k];
  float m = fabsf(v);
  for (int off = 32; off; off >>= 1) m = fmaxf(m, __shfl_xor(m, off, 64));
  __shared__ float smax[4];
  if ((k & 63) == 0) smax[k >> 6] = m;
  __syncthreads();
  float mm = fmaxf(fmaxf(smax[0], smax[1]), fmaxf(smax[2], smax[3]));
  float s = fmaxf(mm, 1e-20f) / 127.f;
  int qv = (int)rintf(v / s);
  qv = min(127, max(-127, qv));
  wq[row * NH + k] = (int8_t)qv;
  if (k == 0) scale[row] = s;
}

// Round-0 champion structure (pure sdot4, 2 lanes/unit), de-AGPR'd.
//
// KEY CHANGE vs round-0: __launch_bounds__(512, 2) caps the unified
// register budget at 256/wave (we need 2 waves/SIMD residency anyway).
// Round-0's (512,1) granted 512 (256 VGPR + 256 AGPR) and the allocator
// parked the 128-int weight arrays in AGPRs (VGPR_Count=96 proves it);
// sdot4 cannot read AGPRs, so every one of the 128 dots/step paid a
// v_accvgpr_read: ~512 cyc/SIMD/step = 24% of the step. Demand is ~218
// regs; under a 256 cap the arrays must become arch VGPRs.
// Also: single h copy (one write/unit/step instead of two); the
// single-copy broadcast read pattern is verified (rounds 6/8 V-path).
//
// Evidence from rounds 5/6/8: MFMA and VALU phases of barrier-locked
// waves SERIALIZE (pipes sum, not max) — so the MFMA route is capped at
// ~1.8ms and the VALU-only route with minimal instruction count wins.
__global__ __launch_bounds__(512, 2)
void lstm_main(const float* __restrict__ x,
               const float* __restrict__ w_ih,
               const float* __restrict__ b_ih,
               const float* __restrict__ b_hh,
               const float* __restrict__ w_out,
               const float* __restrict__ b_out,
               const int8_t* __restrict__ wq,
               const float* __restrict__ scales,
               float* __restrict__ out) {
  const int t = threadIdx.x;   // 0..511
  const int u = t >> 1;        // hidden unit 0..255
  const int half = t & 1;      // k-half
  const int b = blockIdx.x;

  __shared__ __align__(16) int8_t hq[2][NH];  // h state, 2 phases, linear
  __shared__ __align__(16) f16 xs[64][NC];    // 2 KB staged x
  __shared__ float hT[NH];
  __shared__ float lg[NO];

  // ---------------- one-time loads ----------------
  int wi_[32], wf_[32], wg_[32], wo_[32];  // 4 gate half-rows, packed i8x4
  {
    const int4* pi = (const int4*)(wq + (size_t)u * NH + 128 * half);
    const int4* pf = (const int4*)(wq + (size_t)(256 + u) * NH + 128 * half);
    const int4* pg = (const int4*)(wq + (size_t)(512 + u) * NH + 128 * half);
    const int4* po = (const int4*)(wq + (size_t)(768 + u) * NH + 128 * half);
#pragma unroll
    for (int c = 0; c < 8; ++c) {
      int4 vi = pi[c], vf = pf[c], vg = pg[c], vo = po[c];
      wi_[4 * c + 0] = vi.x; wi_[4 * c + 1] = vi.y; wi_[4 * c + 2] = vi.z; wi_[4 * c + 3] = vi.w;
      wf_[4 * c + 0] = vf.x; wf_[4 * c + 1] = vf.y; wf_[4 * c + 2] = vf.z; wf_[4 * c + 3] = vf.w;
      wg_[4 * c + 0] = vg.x; wg_[4 * c + 1] = vg.y; wg_[4 * c + 2] = vg.z; wg_[4 * c + 3] = vg.w;
      wo_[4 * c + 0] = vo.x; wo_[4 * c + 1] = vo.y; wo_[4 * c + 2] = vo.z; wo_[4 * c + 3] = vo.w;
    }
  }
  h2 wih[4][4];  // w_ih half-rows (8 ch) x 4 gates
#pragma unroll
  for (int g4 = 0; g4 < 4; ++g4) {
    int row = u + 256 * g4;
#pragma unroll
    for (int uu = 0; uu < 4; ++uu) {
      h2 t2 = {(f16)w_ih[row * NC + 8 * half + 2 * uu],
               (f16)w_ih[row * NC + 8 * half + 2 * uu + 1]};
      wih[g4][uu] = t2;
    }
  }
  const float K = 1.f / 127.f;
  float sci = scales[u] * K;
  float scf = scales[256 + u] * K;
  float scg = scales[512 + u] * K;
  float sco = scales[768 + u] * K;
  // biases only in half 0 (added exactly once per gate sum)
  float bi_ = half ? 0.f : b_ih[u] + b_hh[u];
  float bf_ = half ? 0.f : b_ih[256 + u] + b_hh[256 + u];
  float bg_ = half ? 0.f : b_ih[512 + u] + b_hh[512 + u];
  float bo_ = half ? 0.f : b_ih[768 + u] + b_hh[768 + u];

  // zero h phase buffers (512 B), stage x chunk 0
  ((int8_t*)hq)[t] = 0;
#pragma unroll
  for (int r = 0; r < 2; ++r) {
    int e = t + 512 * r;  // 0..1023 over (c, tt)
    int cc = e >> 6, tt = e & 63;
    xs[tt][cc] = (f16)x[(size_t)(b * NC + cc) * NT + tt];
  }
  __syncthreads();

  // ---------------- recurrence ----------------
  float c_ = 0.f, h_last = 0.f;

#pragma unroll 1
  for (int s = 0; s < NT; ++s) {
    const int p = s & 1;
    // this half's 128 h bytes: 32 lanes/wave share 8 broadcast addresses
    const int4* hrd = (const int4*)(hq[p] + 128 * half);

    float fi = bi_, ff = bf_, fg_ = bg_, fo = bo_;
    // x projection: this half's 8 channels = 4 f16 pairs (f32 acc)
    {
      h8 xv = *(const h8*)&xs[s & 63][8 * half];
#pragma unroll
      for (int uu = 0; uu < 4; ++uu) {
        h2 xp = {xv[2 * uu], xv[2 * uu + 1]};
        fi = fdot2(xp, wih[0][uu], fi);
        ff = fdot2(xp, wih[1][uu], ff);
        fg_ = fdot2(xp, wih[2][uu], fg_);
        fo = fdot2(xp, wih[3][uu], fo);
      }
    }

    // recurrent dots over this thread's 128-wide k-half (i8 x i8 -> i32)
    int ai = 0, af = 0, ag = 0, ao = 0;
#pragma unroll
    for (int c = 0; c < 8; ++c) {
      int4 hv = hrd[c];
      ai = sdot4(hv.x, wi_[4 * c + 0], ai); ai = sdot4(hv.y, wi_[4 * c + 1], ai);
      ai = sdot4(hv.z, wi_[4 * c + 2], ai); ai = sdot4(hv.w, wi_[4 * c + 3], ai);
      af = sdot4(hv.x, wf_[4 * c + 0], af); af = sdot4(hv.y, wf_[4 * c + 1], af);
      af = sdot4(hv.z, wf_[4 * c + 2], af); af = sdot4(hv.w, wf_[4 * c + 3], af);
      ag = sdot4(hv.x, wg_[4 * c + 0], ag); ag = sdot4(hv.y, wg_[4 * c + 1], ag);
      ag = sdot4(hv.z, wg_[4 * c + 2], ag); ag = sdot4(hv.w, wg_[4 * c + 3], ag);
      ao = sdot4(hv.x, wo_[4 * c + 0], ao); ao = sdot4(hv.y, wo_[4 * c + 1], ao);
      ao = sdot4(hv.z, wo_[4 * c + 2], ao); ao = sdot4(hv.w, wo_[4 * c + 3], ao);
    }

    // dequantize per lane, then pair-reduce (lanes 2u,2u+1) via DPP;
    // result bit-identical on both lanes.
    float vi = fi + (float)ai * sci;
    float vf = ff + (float)af * scf;
    float vg = fg_ + (float)ag * scg;
    float vo = fo + (float)ao * sco;
    vi += pairswap(vi); vf += pairswap(vf); vg += pairswap(vg); vo += pairswap(vo);

    float ig = sigm(vi);
    float fgate = sigm(vf);
    float gv = tanh_(vg);
    float og = sigm(vo);
    c_ = fgate * c_ + ig * gv;
    float hh = og * tanh_(c_);
    h_last = hh;
    // quantize h (|hh| < 1); single copy, one writer per unit
    if (!half) hq[1 - p][u] = (int8_t)(int)rintf(hh * 127.f);

    // restage x every 64 steps (extra barrier protects WAR on xs)
    if ((s & 63) == 63 && s != NT - 1) {
      __syncthreads();
#pragma unroll
      for (int r = 0; r < 2; ++r) {
        int e = t + 512 * r;
        int cc = e >> 6, tt = e & 63;
        xs[tt][cc] = (f16)x[(size_t)(b * NC + cc) * NT + (s + 1) + tt];
      }
    }
    __syncthreads();
  }

  // ---------------- head: logits + log_softmax ----------------
  if (!half) hT[u] = h_last;
  __syncthreads();
  if (t < NO) {
    float acc = b_out[t];
    for (int k = 0; k < NH; ++k) acc += hT[k] * w_out[t * NH + k];
    lg[t] = acc;
  }
  __syncthreads();
  if (t == 0) {
    float m = lg[0];
    for (int o = 1; o < NO; ++o) m = fmaxf(m, lg[o]);
    float ssum = 0.f;
    for (int o = 0; o < NO; ++o) ssum += __expf(lg[o] - m);
    float lse = m + __logf(ssum);
    for (int o = 0; o < NO; ++o) out[b * NO + o] = lg[o] - lse;
  }
}

extern "C" void kernel_launch(void* const* d_in, const int* in_sizes, int n_in,
                              void* d_out, int out_size, void* d_ws, size_t ws_size,
                              hipStream_t stream) {
  const float* x    = (const float*)d_in[0];
  const float* wih  = (const float*)d_in[1];
  const float* whh  = (const float*)d_in[2];
  const float* bih  = (const float*)d_in[3];
  const float* bhh  = (const float*)d_in[4];
  const float* wout = (const float*)d_in[5];
  const float* bout = (const float*)d_in[6];
  float* out = (float*)d_out;
  int8_t* wq = (int8_t*)d_ws;                       // 256 KB i8 w_hh
  float* scales = (float*)((char*)d_ws + NG * NH);  // 4 KB row scales

  hipLaunchKernelGGL(prepack_whh_i8, dim3(NG), dim3(NH), 0, stream, whh, wq, scales);
  hipLaunchKernelGGL(lstm_main, dim3(NB), dim3(512), 0, stream,
                     x, wih, bih, bhh, wout, bout, wq, scales, out);
}